// Round 10
// baseline (11441.674 us; speedup 1.0000x reference)
//
#include <hip/hip_runtime.h>

#define CIN  32
#define COUT 64
#define KK   27
#define EPSV 1e-5f

// ---------- bf16 helpers (manual, RNE) ----------
__device__ __forceinline__ float bf_lo(unsigned u) { return __uint_as_float(u << 16); }
__device__ __forceinline__ float bf_hi(unsigned u) { return __uint_as_float(u & 0xffff0000u); }
__device__ __forceinline__ unsigned f2bf(float x) {
    unsigned u = __float_as_uint(x);
    return (u + 0x7fffu + ((u >> 16) & 1u)) >> 16;
}
__device__ __forceinline__ unsigned pack2(float a, float b) { return f2bf(a) | (f2bf(b) << 16); }

// ---------- conv1: gather fp32 feats rows (nbr1), GEMM -> t1 fp32 + t1h bf16 ----------
__global__ __launch_bounds__(256) void k_conv1(
    const float* __restrict__ feats, const int* __restrict__ nbr,
    const float* __restrict__ W, float* __restrict__ t1, unsigned* __restrict__ t1h, int n)
{
    int p  = blockIdx.x * 256 + threadIdx.x;
    int pc = p < n ? p : n - 1;
    float acc[COUT];
#pragma unroll
    for (int c = 0; c < COUT; c++) acc[c] = 0.f;
    const int* np = nbr + pc * KK;

    float4 b0[8], b1[8];
    int idx0 = np[0];
    {
        const float4* r = (const float4*)(feats + (size_t)idx0 * CIN);
#pragma unroll
        for (int q = 0; q < 8; q++) b0[q] = r[q];
    }
    int idx1 = np[1];

#pragma unroll 1
    for (int k = 0; k < KK; k++) {
        {   // issue next row's loads (prefetch)
            const float4* r = (const float4*)(feats + (size_t)idx1 * CIN);
#pragma unroll
            for (int q = 0; q < 8; q++) b1[q] = r[q];
        }
        idx1 = np[(k + 2) < KK ? (k + 2) : (KK - 1)];
        const float* Wk = W + k * (CIN * COUT);
#pragma unroll 2
        for (int q = 0; q < 8; q++) {
            float fv[4] = {b0[q].x, b0[q].y, b0[q].z, b0[q].w};
#pragma unroll
            for (int e = 0; e < 4; e++) {
                float fj = fv[e];
                const float* wr = Wk + (q * 4 + e) * COUT;  // wave-uniform -> s_load
#pragma unroll
                for (int c = 0; c < COUT; c++) acc[c] = fmaf(fj, wr[c], acc[c]);
            }
        }
#pragma unroll
        for (int q = 0; q < 8; q++) b0[q] = b1[q];
    }
    if (p < n) {
        float4* o = (float4*)(t1 + (size_t)p * COUT);
#pragma unroll
        for (int q = 0; q < COUT / 4; q++)
            o[q] = make_float4(acc[4*q], acc[4*q+1], acc[4*q+2], acc[4*q+3]);
        uint4* oh = (uint4*)(t1h + (size_t)p * (COUT / 2));
#pragma unroll
        for (int q = 0; q < COUT / 8; q++) {
            uint4 h;
            h.x = pack2(acc[8*q+0], acc[8*q+1]);
            h.y = pack2(acc[8*q+2], acc[8*q+3]);
            h.z = pack2(acc[8*q+4], acc[8*q+5]);
            h.w = pack2(acc[8*q+6], acc[8*q+7]);
            oh[q] = h;
        }
    }
}

// ---------- per-channel sum / sumsq of an [n,64] fp32 array ----------
__global__ __launch_bounds__(256) void k_sum(const float* __restrict__ x, int n,
                                             float* __restrict__ S)
{
    __shared__ float ls[2 * COUT];
    if (threadIdx.x < 2 * COUT) ls[threadIdx.x] = 0.f;
    __syncthreads();
    long long total4 = (long long)n * (COUT / 4);
    long long stride = (long long)gridDim.x * 256;
    float s0 = 0, s1 = 0, s2 = 0, s3 = 0, q0 = 0, q1 = 0, q2 = 0, q3 = 0;
    for (long long i = (long long)blockIdx.x * 256 + threadIdx.x; i < total4; i += stride) {
        float4 v = ((const float4*)x)[i];
        s0 += v.x; q0 += v.x * v.x;
        s1 += v.y; q1 += v.y * v.y;
        s2 += v.z; q2 += v.z * v.z;
        s3 += v.w; q3 += v.w * v.w;
    }
    int cb = (threadIdx.x * 4) & (COUT - 1);
    atomicAdd(&ls[cb + 0], s0); atomicAdd(&ls[cb + 1], s1);
    atomicAdd(&ls[cb + 2], s2); atomicAdd(&ls[cb + 3], s3);
    atomicAdd(&ls[COUT + cb + 0], q0); atomicAdd(&ls[COUT + cb + 1], q1);
    atomicAdd(&ls[COUT + cb + 2], q2); atomicAdd(&ls[COUT + cb + 3], q3);
    __syncthreads();
    if (threadIdx.x < 2 * COUT) atomicAdd(&S[threadIdx.x], ls[threadIdx.x]);
}

// ---------- conv2: gather bf16 t1h rows, fused bn1+relu, GEMM -> t2 fp32 ----------
__global__ __launch_bounds__(256) void k_conv2(
    const unsigned* __restrict__ t1h, const int* __restrict__ nbr,
    const float* __restrict__ W, const float* __restrict__ S,
    const float* __restrict__ g, const float* __restrict__ b,
    float* __restrict__ t2, int n, float invn)
{
    __shared__ float sA[COUT], sB[COUT];
    if (threadIdx.x < COUT) {
        int c = threadIdx.x;
        float mu  = S[c] * invn;
        float var = fmaxf(S[COUT + c] * invn - mu * mu, 0.f);
        float a   = g[c] * rsqrtf(var + EPSV);
        sA[c] = a; sB[c] = b[c] - mu * a;
    }
    __syncthreads();
    int p  = blockIdx.x * 256 + threadIdx.x;
    int pc = p < n ? p : n - 1;
    float acc[COUT];
#pragma unroll
    for (int c = 0; c < COUT; c++) acc[c] = 0.f;
    const int* np = nbr + pc * KK;

    uint4 b0[8], b1[8];
    int idx0 = np[0];
    {
        const uint4* r = (const uint4*)(t1h + (size_t)idx0 * (COUT / 2));
#pragma unroll
        for (int q = 0; q < 8; q++) b0[q] = r[q];
    }
    int idx1 = np[1];

#pragma unroll 1
    for (int k = 0; k < KK; k++) {
        {   // prefetch next row
            const uint4* r = (const uint4*)(t1h + (size_t)idx1 * (COUT / 2));
#pragma unroll
            for (int q = 0; q < 8; q++) b1[q] = r[q];
        }
        idx1 = np[(k + 2) < KK ? (k + 2) : (KK - 1)];
        const float* Wk = W + k * (COUT * COUT);
#pragma unroll
        for (int jc = 0; jc < 4; jc++) {
            float f[16];
#pragma unroll
            for (int h = 0; h < 2; h++) {
                uint4 v = b0[jc * 2 + h];
                f[h*8+0] = bf_lo(v.x); f[h*8+1] = bf_hi(v.x);
                f[h*8+2] = bf_lo(v.y); f[h*8+3] = bf_hi(v.y);
                f[h*8+4] = bf_lo(v.z); f[h*8+5] = bf_hi(v.z);
                f[h*8+6] = bf_lo(v.w); f[h*8+7] = bf_hi(v.w);
            }
#pragma unroll
            for (int jj = 0; jj < 16; jj++) {
                int j = jc * 16 + jj;
                f[jj] = fmaxf(fmaf(f[jj], sA[j], sB[j]), 0.f);  // bn1+relu
            }
#pragma unroll 2
            for (int jj = 0; jj < 16; jj++) {
                float fj = f[jj];
                const float* wr = Wk + (jc * 16 + jj) * COUT;   // wave-uniform -> s_load
#pragma unroll
                for (int c = 0; c < COUT; c++) acc[c] = fmaf(fj, wr[c], acc[c]);
            }
        }
#pragma unroll
        for (int q = 0; q < 8; q++) b0[q] = b1[q];
    }
    if (p < n) {
        float4* o = (float4*)(t2 + (size_t)p * COUT);
#pragma unroll
        for (int q = 0; q < COUT / 4; q++)
            o[q] = make_float4(acc[4*q], acc[4*q+1], acc[4*q+2], acc[4*q+3]);
    }
}

// ---------- x0 = relu(bn2(t2)) + feats@Wlin -> x0f fp32 (in-place over t2) + x0h bf16 ----------
// NOTE: t2 and x0f may alias (same buffer, row-to-row) -> no __restrict__ on them.
__global__ __launch_bounds__(256) void k_x0(
    const float* t2, const float* __restrict__ feats,
    const float* __restrict__ S, const float* __restrict__ g, const float* __restrict__ b,
    const float* __restrict__ Wlin, float* x0f, unsigned* __restrict__ x0h,
    int n, float invn)
{
    __shared__ float sA[COUT], sB[COUT];
    if (threadIdx.x < COUT) {
        int c = threadIdx.x;
        float mu  = S[c] * invn;
        float var = fmaxf(S[COUT + c] * invn - mu * mu, 0.f);
        float a   = g[c] * rsqrtf(var + EPSV);
        sA[c] = a; sB[c] = b[c] - mu * a;
    }
    __syncthreads();
    int p  = blockIdx.x * 256 + threadIdx.x;
    int pc = p < n ? p : n - 1;
    float f[CIN];
    {
        const float4* fr = (const float4*)(feats + (size_t)pc * CIN);
#pragma unroll
        for (int q = 0; q < CIN / 4; q++) {
            float4 v = fr[q];
            f[4*q+0] = v.x; f[4*q+1] = v.y; f[4*q+2] = v.z; f[4*q+3] = v.w;
        }
    }
    float acc[COUT];
    {
        const float4* tr = (const float4*)(t2 + (size_t)pc * COUT);
#pragma unroll
        for (int q = 0; q < COUT / 4; q++) {
            float4 v = tr[q];
            acc[4*q+0] = fmaxf(fmaf(v.x, sA[4*q+0], sB[4*q+0]), 0.f);
            acc[4*q+1] = fmaxf(fmaf(v.y, sA[4*q+1], sB[4*q+1]), 0.f);
            acc[4*q+2] = fmaxf(fmaf(v.z, sA[4*q+2], sB[4*q+2]), 0.f);
            acc[4*q+3] = fmaxf(fmaf(v.w, sA[4*q+3], sB[4*q+3]), 0.f);
        }
    }
#pragma unroll 4
    for (int j = 0; j < CIN; j++) {
        float fj = f[j];
        const float* wr = Wlin + j * COUT;     // wave-uniform -> s_load
#pragma unroll
        for (int c = 0; c < COUT; c++) acc[c] = fmaf(fj, wr[c], acc[c]);
    }
    if (p < n) {
        float4* o = (float4*)(x0f + (size_t)p * COUT);
#pragma unroll
        for (int q = 0; q < COUT / 4; q++)
            o[q] = make_float4(acc[4*q], acc[4*q+1], acc[4*q+2], acc[4*q+3]);
        uint4* oh = (uint4*)(x0h + (size_t)p * (COUT / 2));
#pragma unroll
        for (int q = 0; q < COUT / 8; q++) {
            uint4 h;
            h.x = pack2(acc[8*q+0], acc[8*q+1]);
            h.y = pack2(acc[8*q+2], acc[8*q+3]);
            h.z = pack2(acc[8*q+4], acc[8*q+5]);
            h.w = pack2(acc[8*q+6], acc[8*q+7]);
            oh[q] = h;
        }
    }
}

// ---------- pool: y = mean over 27 gathered bf16 rows (fp32 accumulate) ----------
__global__ __launch_bounds__(256) void k_pool(
    const unsigned* __restrict__ x, const int* __restrict__ nbr,
    unsigned* __restrict__ y, int n)
{
    int p  = blockIdx.x * 256 + threadIdx.x;
    int pc = p < n ? p : n - 1;
    float acc[COUT];
#pragma unroll
    for (int c = 0; c < COUT; c++) acc[c] = 0.f;
    const int* np = nbr + pc * KK;

    uint4 b0[8], b1[8];
    int idx0 = np[0];
    {
        const uint4* r = (const uint4*)(x + (size_t)idx0 * (COUT / 2));
#pragma unroll
        for (int q = 0; q < 8; q++) b0[q] = r[q];
    }
    int idx1 = np[1];

#pragma unroll 1
    for (int k = 0; k < KK; k++) {
        {
            const uint4* r = (const uint4*)(x + (size_t)idx1 * (COUT / 2));
#pragma unroll
            for (int q = 0; q < 8; q++) b1[q] = r[q];
        }
        idx1 = np[(k + 2) < KK ? (k + 2) : (KK - 1)];
#pragma unroll
        for (int q = 0; q < 8; q++) {
            uint4 v = b0[q];
            acc[q*8+0] += bf_lo(v.x); acc[q*8+1] += bf_hi(v.x);
            acc[q*8+2] += bf_lo(v.y); acc[q*8+3] += bf_hi(v.y);
            acc[q*8+4] += bf_lo(v.z); acc[q*8+5] += bf_hi(v.z);
            acc[q*8+6] += bf_lo(v.w); acc[q*8+7] += bf_hi(v.w);
        }
#pragma unroll
        for (int q = 0; q < 8; q++) b0[q] = b1[q];
    }
    if (p < n) {
        const float inv = 1.f / 27.f;
        uint4* o = (uint4*)(y + (size_t)p * (COUT / 2));
#pragma unroll
        for (int q = 0; q < COUT / 8; q++) {
            uint4 h;
            h.x = pack2(acc[8*q+0]*inv, acc[8*q+1]*inv);
            h.y = pack2(acc[8*q+2]*inv, acc[8*q+3]*inv);
            h.z = pack2(acc[8*q+4]*inv, acc[8*q+5]*inv);
            h.w = pack2(acc[8*q+6]*inv, acc[8*q+7]*inv);
            o[q] = h;
        }
    }
}

// ---------- final2: streaming only. gates = x0@Wsw; out = s0*x0 + s1*(x1*g0+x2*g1+x3*g2) ----------
__global__ __launch_bounds__(192) void k_final2(
    const float* __restrict__ x0f, const unsigned* __restrict__ x1h,
    const unsigned* __restrict__ x2h, const unsigned* __restrict__ x3h,
    const float* __restrict__ Wsw, const float* __restrict__ sc0,
    const float* __restrict__ sc1, float* __restrict__ out, int n)
{
    __shared__ float xs[192 * 65];
    int p  = blockIdx.x * 192 + threadIdx.x;
    int pc = p < n ? p : n - 1;
    float* myx = xs + threadIdx.x * 65;
    {
        const float4* xr = (const float4*)(x0f + (size_t)pc * COUT);
#pragma unroll
        for (int q = 0; q < COUT / 4; q++) {
            float4 v = xr[q];
            myx[4*q+0] = v.x; myx[4*q+1] = v.y; myx[4*q+2] = v.z; myx[4*q+3] = v.w;
        }
    }
    __syncthreads();  // xs fully written per-thread; sync not strictly needed (own row) but cheap

#pragma unroll 1
    for (int ch = 0; ch < 4; ch++) {
        int cb = ch * 16;
        float g0[16], g1[16], g2[16];
#pragma unroll
        for (int i = 0; i < 16; i++) { g0[i] = 0.f; g1[i] = 0.f; g2[i] = 0.f; }
#pragma unroll 2
        for (int j = 0; j < COUT; j++) {
            float fj = myx[j];                    // LDS, conflict-free (stride 65)
            const float* wr = Wsw + j * 192 + cb; // wave-uniform -> s_load
#pragma unroll
            for (int cc = 0; cc < 16; cc++) {
                g0[cc] = fmaf(fj, wr[cc],        g0[cc]);
                g1[cc] = fmaf(fj, wr[64 + cc],   g1[cc]);
                g2[cc] = fmaf(fj, wr[128 + cc],  g2[cc]);
            }
        }
        if (p < n) {
            const uint4* r1 = (const uint4*)(x1h + (size_t)pc * (COUT/2) + cb/2);
            const uint4* r2 = (const uint4*)(x2h + (size_t)pc * (COUT/2) + cb/2);
            const uint4* r3 = (const uint4*)(x3h + (size_t)pc * (COUT/2) + cb/2);
            uint4 a0 = r1[0], a1 = r1[1];
            uint4 b0 = r2[0], b1 = r2[1];
            uint4 c0 = r3[0], c1 = r3[1];
            float x1v[16], x2v[16], x3v[16];
            x1v[0]=bf_lo(a0.x); x1v[1]=bf_hi(a0.x); x1v[2]=bf_lo(a0.y); x1v[3]=bf_hi(a0.y);
            x1v[4]=bf_lo(a0.z); x1v[5]=bf_hi(a0.z); x1v[6]=bf_lo(a0.w); x1v[7]=bf_hi(a0.w);
            x1v[8]=bf_lo(a1.x); x1v[9]=bf_hi(a1.x); x1v[10]=bf_lo(a1.y); x1v[11]=bf_hi(a1.y);
            x1v[12]=bf_lo(a1.z); x1v[13]=bf_hi(a1.z); x1v[14]=bf_lo(a1.w); x1v[15]=bf_hi(a1.w);
            x2v[0]=bf_lo(b0.x); x2v[1]=bf_hi(b0.x); x2v[2]=bf_lo(b0.y); x2v[3]=bf_hi(b0.y);
            x2v[4]=bf_lo(b0.z); x2v[5]=bf_hi(b0.z); x2v[6]=bf_lo(b0.w); x2v[7]=bf_hi(b0.w);
            x2v[8]=bf_lo(b1.x); x2v[9]=bf_hi(b1.x); x2v[10]=bf_lo(b1.y); x2v[11]=bf_hi(b1.y);
            x2v[12]=bf_lo(b1.z); x2v[13]=bf_hi(b1.z); x2v[14]=bf_lo(b1.w); x2v[15]=bf_hi(b1.w);
            x3v[0]=bf_lo(c0.x); x3v[1]=bf_hi(c0.x); x3v[2]=bf_lo(c0.y); x3v[3]=bf_hi(c0.y);
            x3v[4]=bf_lo(c0.z); x3v[5]=bf_hi(c0.z); x3v[6]=bf_lo(c0.w); x3v[7]=bf_hi(c0.w);
            x3v[8]=bf_lo(c1.x); x3v[9]=bf_hi(c1.x); x3v[10]=bf_lo(c1.y); x3v[11]=bf_hi(c1.y);
            x3v[12]=bf_lo(c1.z); x3v[13]=bf_hi(c1.z); x3v[14]=bf_lo(c1.w); x3v[15]=bf_hi(c1.w);
            float ov[16];
#pragma unroll
            for (int cc = 0; cc < 16; cc++) {
                float f2 = x1v[cc] * g0[cc] + x2v[cc] * g1[cc] + x3v[cc] * g2[cc];
                ov[cc] = sc0[cb + cc] * myx[cb + cc] + sc1[cb + cc] * f2;
            }
            float4* o = (float4*)(out + (size_t)p * COUT + cb);
#pragma unroll
            for (int q = 0; q < 4; q++)
                o[q] = make_float4(ov[4*q], ov[4*q+1], ov[4*q+2], ov[4*q+3]);
        }
    }
}

extern "C" void kernel_launch(void* const* d_in, const int* in_sizes, int n_in,
                              void* d_out, int out_size, void* d_ws, size_t ws_size,
                              hipStream_t stream)
{
    const float* feats = (const float*)d_in[0];
    const int*   nbr1  = (const int*)d_in[1];
    const int*   nbr3  = (const int*)d_in[2];
    const int*   nbr9  = (const int*)d_in[3];
    const float* W0a   = (const float*)d_in[4];
    const float* g1    = (const float*)d_in[5];
    const float* b1    = (const float*)d_in[6];
    const float* W0b   = (const float*)d_in[7];
    const float* g2    = (const float*)d_in[8];
    const float* b2    = (const float*)d_in[9];
    const float* Wlin  = (const float*)d_in[10];
    const float* Wsw   = (const float*)d_in[11];
    const float* sc0   = (const float*)d_in[12];
    const float* sc1   = (const float*)d_in[13];

    int n = in_sizes[0] / CIN;   // 400000
    float* base = (float*)d_ws;
    // A: t1 -> t2 -> x0f (in-place reuse), fp32 [n*64]
    // t1h/x0h/x1h/x2h/x3h: bf16-packed [n*32 u32] each; S: stats [256 f32]
    float*    A   = base;
    unsigned* t1h = (unsigned*)(base + (size_t)n * COUT);
    unsigned* x0h = t1h + (size_t)n * (COUT / 2);
    unsigned* x1h = x0h + (size_t)n * (COUT / 2);
    unsigned* x2h = x1h + (size_t)n * (COUT / 2);
    unsigned* x3h = x2h + (size_t)n * (COUT / 2);
    float*    S   = (float*)(x3h + (size_t)n * (COUT / 2));
    float*    out = (float*)d_out;
    float invn = 1.0f / (float)n;

    int grid  = (n + 255) / 256;
    int gridF = (n + 191) / 192;

    hipMemsetAsync(S, 0, 256 * sizeof(float), stream);
    k_conv1<<<grid, 256, 0, stream>>>(feats, nbr1, W0a, A, t1h, n);
    k_sum<<<2048, 256, 0, stream>>>(A, n, S);
    k_conv2<<<grid, 256, 0, stream>>>(t1h, nbr1, W0b, S, g1, b1, A, n, invn);   // t2 overwrites t1 (dead)
    k_sum<<<2048, 256, 0, stream>>>(A, n, S + 128);
    k_x0<<<grid, 256, 0, stream>>>(A, feats, S + 128, g2, b2, Wlin, A, x0h, n, invn); // x0f in-place
    k_pool<<<grid, 256, 0, stream>>>(x0h, nbr1, x1h, n);
    k_pool<<<grid, 256, 0, stream>>>(x1h, nbr3, x2h, n);
    k_pool<<<grid, 256, 0, stream>>>(x2h, nbr9, x3h, n);
    k_final2<<<gridF, 192, 0, stream>>>(A, x1h, x2h, x3h, Wsw, sc0, sc1, out, n);
}

// Round 11
// 4570.154 us; speedup vs baseline: 2.5036x; 2.5036x over previous
//
#include <hip/hip_runtime.h>

#define CIN  32
#define COUT 64
#define KK   27
#define EPSV 1e-5f

// ---------- bf16 helpers (manual, RNE) ----------
__device__ __forceinline__ float bf_lo(unsigned u) { return __uint_as_float(u << 16); }
__device__ __forceinline__ float bf_hi(unsigned u) { return __uint_as_float(u & 0xffff0000u); }
__device__ __forceinline__ unsigned f2bf(float x) {
    unsigned u = __float_as_uint(x);
    return (u + 0x7fffu + ((u >> 16) & 1u)) >> 16;
}
__device__ __forceinline__ unsigned pack2(float a, float b) { return f2bf(a) | (f2bf(b) << 16); }

// ---------- conv1: gather fp32 feats rows; 2 threads/point (output split) ----------
// block 256 = 128 points x 2 halves; half = tid>>7 (wave-uniform, readfirstlane'd)
__global__ __launch_bounds__(256) void k_conv1(
    const float* __restrict__ feats, const int* __restrict__ nbr,
    const float* __restrict__ W, float* __restrict__ t1, unsigned* __restrict__ t1h, int n)
{
    int half = __builtin_amdgcn_readfirstlane(threadIdx.x >> 7);  // SGPR -> weight s_load stays uniform
    int cbase = half * 32;
    int p  = blockIdx.x * 128 + (threadIdx.x & 127);
    int pc = p < n ? p : n - 1;
    float acc[32];
#pragma unroll
    for (int c = 0; c < 32; c++) acc[c] = 0.f;
    const int* np = nbr + (size_t)pc * KK;

#pragma unroll 1
    for (int k = 0; k < KK; k++) {
        int idx = np[k];
        const float4* fr = (const float4*)(feats + (size_t)idx * CIN);
        float4 b[8];
#pragma unroll
        for (int q = 0; q < 8; q++) b[q] = fr[q];   // all 8 loads in flight
        const float* Wk = W + k * (CIN * COUT) + cbase;
#pragma unroll 2
        for (int q = 0; q < 8; q++) {
            float fv[4] = {b[q].x, b[q].y, b[q].z, b[q].w};
#pragma unroll
            for (int e = 0; e < 4; e++) {
                float fj = fv[e];
                const float* wr = Wk + (q * 4 + e) * COUT;  // wave-uniform -> s_load
#pragma unroll
                for (int c = 0; c < 32; c++) acc[c] = fmaf(fj, wr[c], acc[c]);
            }
        }
    }
    if (p < n) {
        float4* o = (float4*)(t1 + (size_t)p * COUT + cbase);
#pragma unroll
        for (int q = 0; q < 8; q++)
            o[q] = make_float4(acc[4*q], acc[4*q+1], acc[4*q+2], acc[4*q+3]);
        uint4* oh = (uint4*)(t1h + (size_t)p * (COUT / 2) + half * 16);
#pragma unroll
        for (int q = 0; q < 4; q++) {
            uint4 h;
            h.x = pack2(acc[8*q+0], acc[8*q+1]);
            h.y = pack2(acc[8*q+2], acc[8*q+3]);
            h.z = pack2(acc[8*q+4], acc[8*q+5]);
            h.w = pack2(acc[8*q+6], acc[8*q+7]);
            oh[q] = h;
        }
    }
}

// ---------- per-channel sum / sumsq of an [n,64] fp32 array ----------
__global__ __launch_bounds__(256) void k_sum(const float* __restrict__ x, int n,
                                             float* __restrict__ S)
{
    __shared__ float ls[2 * COUT];
    if (threadIdx.x < 2 * COUT) ls[threadIdx.x] = 0.f;
    __syncthreads();
    long long total4 = (long long)n * (COUT / 4);
    long long stride = (long long)gridDim.x * 256;
    float s0 = 0, s1 = 0, s2 = 0, s3 = 0, q0 = 0, q1 = 0, q2 = 0, q3 = 0;
    for (long long i = (long long)blockIdx.x * 256 + threadIdx.x; i < total4; i += stride) {
        float4 v = ((const float4*)x)[i];
        s0 += v.x; q0 += v.x * v.x;
        s1 += v.y; q1 += v.y * v.y;
        s2 += v.z; q2 += v.z * v.z;
        s3 += v.w; q3 += v.w * v.w;
    }
    int cb = (threadIdx.x * 4) & (COUT - 1);
    atomicAdd(&ls[cb + 0], s0); atomicAdd(&ls[cb + 1], s1);
    atomicAdd(&ls[cb + 2], s2); atomicAdd(&ls[cb + 3], s3);
    atomicAdd(&ls[COUT + cb + 0], q0); atomicAdd(&ls[COUT + cb + 1], q1);
    atomicAdd(&ls[COUT + cb + 2], q2); atomicAdd(&ls[COUT + cb + 3], q3);
    __syncthreads();
    if (threadIdx.x < 2 * COUT) atomicAdd(&S[threadIdx.x], ls[threadIdx.x]);
}

// ---------- conv2: gather bf16 rows, fused bn1+relu; 2 threads/point (output split) ----------
__global__ __launch_bounds__(256) void k_conv2(
    const unsigned* __restrict__ t1h, const int* __restrict__ nbr,
    const float* __restrict__ W, const float* __restrict__ S,
    const float* __restrict__ g, const float* __restrict__ b,
    float* __restrict__ t2, int n, float invn)
{
    __shared__ float sA[COUT], sB[COUT];
    if (threadIdx.x < COUT) {
        int c = threadIdx.x;
        float mu  = S[c] * invn;
        float var = fmaxf(S[COUT + c] * invn - mu * mu, 0.f);
        float a   = g[c] * rsqrtf(var + EPSV);
        sA[c] = a; sB[c] = b[c] - mu * a;
    }
    __syncthreads();
    int half = __builtin_amdgcn_readfirstlane(threadIdx.x >> 7);
    int cbase = half * 32;
    int p  = blockIdx.x * 128 + (threadIdx.x & 127);
    int pc = p < n ? p : n - 1;
    float acc[32];
#pragma unroll
    for (int c = 0; c < 32; c++) acc[c] = 0.f;
    const int* np = nbr + (size_t)pc * KK;

#pragma unroll 1
    for (int k = 0; k < KK; k++) {
        int idx = np[k];
        const uint4* fr = (const uint4*)(t1h + (size_t)idx * (COUT / 2));
        uint4 bv[8];
#pragma unroll
        for (int q = 0; q < 8; q++) bv[q] = fr[q];  // all 8 loads in flight
        const float* Wk = W + k * (COUT * COUT) + cbase;
#pragma unroll 1
        for (int jc = 0; jc < 4; jc++) {
            float f[16];
#pragma unroll
            for (int h = 0; h < 2; h++) {
                uint4 v = bv[jc * 2 + h];
                f[h*8+0] = bf_lo(v.x); f[h*8+1] = bf_hi(v.x);
                f[h*8+2] = bf_lo(v.y); f[h*8+3] = bf_hi(v.y);
                f[h*8+4] = bf_lo(v.z); f[h*8+5] = bf_hi(v.z);
                f[h*8+6] = bf_lo(v.w); f[h*8+7] = bf_hi(v.w);
            }
#pragma unroll
            for (int jj = 0; jj < 16; jj++) {
                int j = jc * 16 + jj;
                f[jj] = fmaxf(fmaf(f[jj], sA[j], sB[j]), 0.f);  // bn1+relu
            }
#pragma unroll 4
            for (int jj = 0; jj < 16; jj++) {
                float fj = f[jj];
                const float* wr = Wk + (jc * 16 + jj) * COUT;   // wave-uniform -> s_load
#pragma unroll
                for (int c = 0; c < 32; c++) acc[c] = fmaf(fj, wr[c], acc[c]);
            }
        }
    }
    if (p < n) {
        float4* o = (float4*)(t2 + (size_t)p * COUT + cbase);
#pragma unroll
        for (int q = 0; q < 8; q++)
            o[q] = make_float4(acc[4*q], acc[4*q+1], acc[4*q+2], acc[4*q+3]);
    }
}

// ---------- x0 = relu(bn2(t2)) + feats@Wlin -> x0f fp32 (in-place) + x0h bf16 ----------
__global__ __launch_bounds__(256) void k_x0(
    const float* t2, const float* __restrict__ feats,
    const float* __restrict__ S, const float* __restrict__ g, const float* __restrict__ b,
    const float* __restrict__ Wlin, float* x0f, unsigned* __restrict__ x0h,
    int n, float invn)
{
    __shared__ float sA[COUT], sB[COUT];
    if (threadIdx.x < COUT) {
        int c = threadIdx.x;
        float mu  = S[c] * invn;
        float var = fmaxf(S[COUT + c] * invn - mu * mu, 0.f);
        float a   = g[c] * rsqrtf(var + EPSV);
        sA[c] = a; sB[c] = b[c] - mu * a;
    }
    __syncthreads();
    int p  = blockIdx.x * 256 + threadIdx.x;
    int pc = p < n ? p : n - 1;
    float f[CIN];
    {
        const float4* fr = (const float4*)(feats + (size_t)pc * CIN);
#pragma unroll
        for (int q = 0; q < CIN / 4; q++) {
            float4 v = fr[q];
            f[4*q+0] = v.x; f[4*q+1] = v.y; f[4*q+2] = v.z; f[4*q+3] = v.w;
        }
    }
    float acc[COUT];
    {
        const float4* tr = (const float4*)(t2 + (size_t)pc * COUT);
#pragma unroll
        for (int q = 0; q < COUT / 4; q++) {
            float4 v = tr[q];
            acc[4*q+0] = fmaxf(fmaf(v.x, sA[4*q+0], sB[4*q+0]), 0.f);
            acc[4*q+1] = fmaxf(fmaf(v.y, sA[4*q+1], sB[4*q+1]), 0.f);
            acc[4*q+2] = fmaxf(fmaf(v.z, sA[4*q+2], sB[4*q+2]), 0.f);
            acc[4*q+3] = fmaxf(fmaf(v.w, sA[4*q+3], sB[4*q+3]), 0.f);
        }
    }
#pragma unroll 4
    for (int j = 0; j < CIN; j++) {
        float fj = f[j];
        const float* wr = Wlin + j * COUT;     // wave-uniform -> s_load
#pragma unroll
        for (int c = 0; c < COUT; c++) acc[c] = fmaf(fj, wr[c], acc[c]);
    }
    if (p < n) {
        float4* o = (float4*)(x0f + (size_t)p * COUT);
#pragma unroll
        for (int q = 0; q < COUT / 4; q++)
            o[q] = make_float4(acc[4*q], acc[4*q+1], acc[4*q+2], acc[4*q+3]);
        uint4* oh = (uint4*)(x0h + (size_t)p * (COUT / 2));
#pragma unroll
        for (int q = 0; q < COUT / 8; q++) {
            uint4 h;
            h.x = pack2(acc[8*q+0], acc[8*q+1]);
            h.y = pack2(acc[8*q+2], acc[8*q+3]);
            h.z = pack2(acc[8*q+4], acc[8*q+5]);
            h.w = pack2(acc[8*q+6], acc[8*q+7]);
            oh[q] = h;
        }
    }
}

// ---------- pool: 2 threads/point (channel split, no duplicate bytes) ----------
// gtid pairs (2i,2i+1) cover point i halves -> adjacent 64B reads coalesce
__global__ __launch_bounds__(256) void k_pool(
    const unsigned* __restrict__ x, const int* __restrict__ nbr,
    unsigned* __restrict__ y, int n)
{
    int gt = blockIdx.x * 256 + threadIdx.x;
    int p  = gt >> 1;
    int half = gt & 1;
    int pc = p < n ? p : n - 1;
    float acc[32];
#pragma unroll
    for (int c = 0; c < 32; c++) acc[c] = 0.f;
    const int* np = nbr + (size_t)pc * KK;

#pragma unroll 1
    for (int k = 0; k < KK; k++) {
        int idx = np[k];
        const uint4* r = (const uint4*)(x + (size_t)idx * (COUT / 2) + half * 16);
        uint4 bv[4];
#pragma unroll
        for (int q = 0; q < 4; q++) bv[q] = r[q];   // 64B: all loads in flight
#pragma unroll
        for (int q = 0; q < 4; q++) {
            uint4 v = bv[q];
            acc[q*8+0] += bf_lo(v.x); acc[q*8+1] += bf_hi(v.x);
            acc[q*8+2] += bf_lo(v.y); acc[q*8+3] += bf_hi(v.y);
            acc[q*8+4] += bf_lo(v.z); acc[q*8+5] += bf_hi(v.z);
            acc[q*8+6] += bf_lo(v.w); acc[q*8+7] += bf_hi(v.w);
        }
    }
    if (p < n) {
        const float inv = 1.f / 27.f;
        uint4* o = (uint4*)(y + (size_t)p * (COUT / 2) + half * 16);
#pragma unroll
        for (int q = 0; q < 4; q++) {
            uint4 h;
            h.x = pack2(acc[8*q+0]*inv, acc[8*q+1]*inv);
            h.y = pack2(acc[8*q+2]*inv, acc[8*q+3]*inv);
            h.z = pack2(acc[8*q+4]*inv, acc[8*q+5]*inv);
            h.w = pack2(acc[8*q+6]*inv, acc[8*q+7]*inv);
            o[q] = h;
        }
    }
}

// ---------- final2: streaming only. gates = x0@Wsw; out = s0*x0 + s1*(x1*g0+x2*g1+x3*g2) ----------
__global__ __launch_bounds__(192) void k_final2(
    const float* __restrict__ x0f, const unsigned* __restrict__ x1h,
    const unsigned* __restrict__ x2h, const unsigned* __restrict__ x3h,
    const float* __restrict__ Wsw, const float* __restrict__ sc0,
    const float* __restrict__ sc1, float* __restrict__ out, int n)
{
    __shared__ float xs[192 * 65];
    int p  = blockIdx.x * 192 + threadIdx.x;
    int pc = p < n ? p : n - 1;
    float* myx = xs + threadIdx.x * 65;
    {
        const float4* xr = (const float4*)(x0f + (size_t)pc * COUT);
#pragma unroll
        for (int q = 0; q < COUT / 4; q++) {
            float4 v = xr[q];
            myx[4*q+0] = v.x; myx[4*q+1] = v.y; myx[4*q+2] = v.z; myx[4*q+3] = v.w;
        }
    }

#pragma unroll 1
    for (int ch = 0; ch < 4; ch++) {
        int cb = ch * 16;
        float g0[16], g1[16], g2[16];
#pragma unroll
        for (int i = 0; i < 16; i++) { g0[i] = 0.f; g1[i] = 0.f; g2[i] = 0.f; }
#pragma unroll 2
        for (int j = 0; j < COUT; j++) {
            float fj = myx[j];                    // LDS, conflict-free (stride 65)
            const float* wr = Wsw + j * 192 + cb; // wave-uniform -> s_load
#pragma unroll
            for (int cc = 0; cc < 16; cc++) {
                g0[cc] = fmaf(fj, wr[cc],        g0[cc]);
                g1[cc] = fmaf(fj, wr[64 + cc],   g1[cc]);
                g2[cc] = fmaf(fj, wr[128 + cc],  g2[cc]);
            }
        }
        if (p < n) {
            const uint4* r1 = (const uint4*)(x1h + (size_t)pc * (COUT/2) + cb/2);
            const uint4* r2 = (const uint4*)(x2h + (size_t)pc * (COUT/2) + cb/2);
            const uint4* r3 = (const uint4*)(x3h + (size_t)pc * (COUT/2) + cb/2);
            uint4 a0 = r1[0], a1 = r1[1];
            uint4 b0 = r2[0], b1 = r2[1];
            uint4 c0 = r3[0], c1 = r3[1];
            float x1v[16], x2v[16], x3v[16];
            x1v[0]=bf_lo(a0.x); x1v[1]=bf_hi(a0.x); x1v[2]=bf_lo(a0.y); x1v[3]=bf_hi(a0.y);
            x1v[4]=bf_lo(a0.z); x1v[5]=bf_hi(a0.z); x1v[6]=bf_lo(a0.w); x1v[7]=bf_hi(a0.w);
            x1v[8]=bf_lo(a1.x); x1v[9]=bf_hi(a1.x); x1v[10]=bf_lo(a1.y); x1v[11]=bf_hi(a1.y);
            x1v[12]=bf_lo(a1.z); x1v[13]=bf_hi(a1.z); x1v[14]=bf_lo(a1.w); x1v[15]=bf_hi(a1.w);
            x2v[0]=bf_lo(b0.x); x2v[1]=bf_hi(b0.x); x2v[2]=bf_lo(b0.y); x2v[3]=bf_hi(b0.y);
            x2v[4]=bf_lo(b0.z); x2v[5]=bf_hi(b0.z); x2v[6]=bf_lo(b0.w); x2v[7]=bf_hi(b0.w);
            x2v[8]=bf_lo(b1.x); x2v[9]=bf_hi(b1.x); x2v[10]=bf_lo(b1.y); x2v[11]=bf_hi(b1.y);
            x2v[12]=bf_lo(b1.z); x2v[13]=bf_hi(b1.z); x2v[14]=bf_lo(b1.w); x2v[15]=bf_hi(b1.w);
            x3v[0]=bf_lo(c0.x); x3v[1]=bf_hi(c0.x); x3v[2]=bf_lo(c0.y); x3v[3]=bf_hi(c0.y);
            x3v[4]=bf_lo(c0.z); x3v[5]=bf_hi(c0.z); x3v[6]=bf_lo(c0.w); x3v[7]=bf_hi(c0.w);
            x3v[8]=bf_lo(c1.x); x3v[9]=bf_hi(c1.x); x3v[10]=bf_lo(c1.y); x3v[11]=bf_hi(c1.y);
            x3v[12]=bf_lo(c1.z); x3v[13]=bf_hi(c1.z); x3v[14]=bf_lo(c1.w); x3v[15]=bf_hi(c1.w);
            float ov[16];
#pragma unroll
            for (int cc = 0; cc < 16; cc++) {
                float f2 = x1v[cc] * g0[cc] + x2v[cc] * g1[cc] + x3v[cc] * g2[cc];
                ov[cc] = sc0[cb + cc] * myx[cb + cc] + sc1[cb + cc] * f2;
            }
            float4* o = (float4*)(out + (size_t)p * COUT + cb);
#pragma unroll
            for (int q = 0; q < 4; q++)
                o[q] = make_float4(ov[4*q], ov[4*q+1], ov[4*q+2], ov[4*q+3]);
        }
    }
}

extern "C" void kernel_launch(void* const* d_in, const int* in_sizes, int n_in,
                              void* d_out, int out_size, void* d_ws, size_t ws_size,
                              hipStream_t stream)
{
    const float* feats = (const float*)d_in[0];
    const int*   nbr1  = (const int*)d_in[1];
    const int*   nbr3  = (const int*)d_in[2];
    const int*   nbr9  = (const int*)d_in[3];
    const float* W0a   = (const float*)d_in[4];
    const float* g1    = (const float*)d_in[5];
    const float* b1    = (const float*)d_in[6];
    const float* W0b   = (const float*)d_in[7];
    const float* g2    = (const float*)d_in[8];
    const float* b2    = (const float*)d_in[9];
    const float* Wlin  = (const float*)d_in[10];
    const float* Wsw   = (const float*)d_in[11];
    const float* sc0   = (const float*)d_in[12];
    const float* sc1   = (const float*)d_in[13];

    int n = in_sizes[0] / CIN;   // 400000
    float* base = (float*)d_ws;
    // A: t1 -> t2 -> x0f (in-place reuse), fp32 [n*64]
    // t1h/x0h/x1h/x2h/x3h: bf16-packed [n*32 u32] each; S: stats [256 f32]
    float*    A   = base;
    unsigned* t1h = (unsigned*)(base + (size_t)n * COUT);
    unsigned* x0h = t1h + (size_t)n * (COUT / 2);
    unsigned* x1h = x0h + (size_t)n * (COUT / 2);
    unsigned* x2h = x1h + (size_t)n * (COUT / 2);
    unsigned* x3h = x2h + (size_t)n * (COUT / 2);
    float*    S   = (float*)(x3h + (size_t)n * (COUT / 2));
    float*    out = (float*)d_out;
    float invn = 1.0f / (float)n;

    int gridH = (n + 127) / 128;   // 2 threads/point kernels
    int grid  = (n + 255) / 256;
    int gridF = (n + 191) / 192;

    hipMemsetAsync(S, 0, 256 * sizeof(float), stream);
    k_conv1<<<gridH, 256, 0, stream>>>(feats, nbr1, W0a, A, t1h, n);
    k_sum<<<2048, 256, 0, stream>>>(A, n, S);
    k_conv2<<<gridH, 256, 0, stream>>>(t1h, nbr1, W0b, S, g1, b1, A, n, invn);  // t2 overwrites t1 (dead)
    k_sum<<<2048, 256, 0, stream>>>(A, n, S + 128);
    k_x0<<<grid, 256, 0, stream>>>(A, feats, S + 128, g2, b2, Wlin, A, x0h, n, invn); // x0f in-place
    k_pool<<<gridH, 256, 0, stream>>>(x0h, nbr1, x1h, n);
    k_pool<<<gridH, 256, 0, stream>>>(x1h, nbr3, x2h, n);
    k_pool<<<gridH, 256, 0, stream>>>(x2h, nbr9, x3h, n);
    k_final2<<<gridF, 192, 0, stream>>>(A, x1h, x2h, x3h, Wsw, sc0, sc1, out, n);
}